// Round 3
// baseline (112.396 us; speedup 1.0000x reference)
//
#include <hip/hip_runtime.h>
#include <hip/hip_cooperative_groups.h>
#include <math.h>

namespace cg = cooperative_groups;

#define B_ 16
#define C_ 2048
#define Q_ 128
#define H_ 128
#define NEGV (-1000000000.0f)
#define REC_ 136  // record: [0]=M, [1]=Z, [8..135]=pq[128]

typedef short short8 __attribute__((ext_vector_type(8)));
typedef float f32x16 __attribute__((ext_vector_type(16)));

__device__ __forceinline__ short f2bf(float f) {
  unsigned u = __builtin_bit_cast(unsigned, f);
  u += 0x7fffu + ((u >> 16) & 1u);
  return (short)(u >> 16);
}
__device__ __forceinline__ float bf2f(short s) {
  unsigned u = ((unsigned)(unsigned short)s) << 16;
  return __builtin_bit_cast(float, u);
}

// swizzled short-index of 16B chunk `chunk16` in row `row` of a [128][128] bf16 tile
__device__ __forceinline__ int swz8(int row, int chunk16) {
  return row * 128 + (((chunk16 ^ (row & 7)) & 15) << 3);
}

__device__ __forceinline__ float wave_max(float v) {
#pragma unroll
  for (int off = 32; off; off >>= 1) v = fmaxf(v, __shfl_xor(v, off, 64));
  return v;
}
__device__ __forceinline__ float wave_sum(float v) {
#pragma unroll
  for (int off = 32; off; off >>= 1) v += __shfl_xor(v, off, 64);
  return v;
}

// Monolithic kernel: per (b, 128-c tile). COOP=1: grid.sync + chunk4 in-kernel.
template <int COOP>
__global__ __launch_bounds__(512, 1) void k_mono(
    const float* __restrict__ ctx, const float* __restrict__ qry,
    const float* __restrict__ W, const int* __restrict__ cmask,
    const int* __restrict__ qmask, float* __restrict__ out,
    float* __restrict__ pw) {
  __shared__ short Qs[16384];   // qry[q][h] bf16, swizzled
  __shared__ short QTs[16384];  // qry^T[h][q] bf16, swizzled
  __shared__ short Xs[16384];   // x=ctx*w_cq; then a[c][q]; then ctx bf16
  __shared__ float scv[128];
  __shared__ float sqm[128];
  __shared__ float pm_lds[2][128];
  __shared__ float ps_lds[2][128];
  __shared__ float mcv[128];    // masked per-c max (for q2c softmax)
  __shared__ float wcv[128];    // exp(mcv - localM)
  __shared__ float pqacc[8][128];
  __shared__ float q2cs[128];

  int b = blockIdx.x >> 4;
  int ct = blockIdx.x & 15;
  int tid = threadIdx.x;
  int bc0 = b * C_ + ct * 128;

  float4 cvr[8];  // this thread's slice of the fp32 ctx tile (kept to the end)

  // ---- stage ctx tile: out chunk1, sc[c], Xs = bf16(ctx*w_cq), cvr regs ----
  {
    int c = tid >> 2, part = tid & 3;
    const float* crow = ctx + (size_t)(bc0 + c) * H_;
    float* orow = out + (size_t)(bc0 + c) * (4 * H_);
    float wsum = 0.f;
#pragma unroll
    for (int jj = 0; jj < 8; jj++) {
      int k = part + 4 * jj;  // float4 chunk 0..31
      float4 v = *(const float4*)&crow[4 * k];
      cvr[jj] = v;
      *(float4*)&orow[4 * k] = v;  // G chunk 1 = ctx (exact fp32)
      float4 wc = *(const float4*)&W[4 * k];
      float4 wq = *(const float4*)&W[2 * H_ + 4 * k];
      wsum += v.x * wc.x + v.y * wc.y + v.z * wc.z + v.w * wc.w;
      short4 xp;
      xp.x = f2bf(v.x * wq.x);
      xp.y = f2bf(v.y * wq.y);
      xp.z = f2bf(v.z * wq.z);
      xp.w = f2bf(v.w * wq.w);
      *(short4*)&Xs[swz8(c, k >> 1) + (k & 1) * 4] = xp;
    }
    wsum += __shfl_xor(wsum, 1, 64);
    wsum += __shfl_xor(wsum, 2, 64);
    if (part == 0) scv[c] = wsum;
  }
  // ---- stage qry (Qs + QTs) and compute sq in-block ----
  {
    int qp = tid >> 3, p = tid & 7;
    const float* q0r = qry + (size_t)(b * Q_ + 2 * qp) * H_;
    const float* q1r = q0r + H_;
    float s0 = 0.f, s1 = 0.f;
#pragma unroll
    for (int jj = 0; jj < 4; jj++) {
      int k = p + 8 * jj;  // float4 chunk 0..31
      float4 v0 = *(const float4*)&q0r[4 * k];
      float4 v1 = *(const float4*)&q1r[4 * k];
      float4 wq4 = *(const float4*)&W[H_ + 4 * k];
      s0 += v0.x * wq4.x + v0.y * wq4.y + v0.z * wq4.z + v0.w * wq4.w;
      s1 += v1.x * wq4.x + v1.y * wq4.y + v1.z * wq4.z + v1.w * wq4.w;
      short4 p0, p1;
      p0.x = f2bf(v0.x); p0.y = f2bf(v0.y); p0.z = f2bf(v0.z); p0.w = f2bf(v0.w);
      p1.x = f2bf(v1.x); p1.y = f2bf(v1.y); p1.z = f2bf(v1.z); p1.w = f2bf(v1.w);
      *(short4*)&Qs[swz8(2 * qp, k >> 1) + (k & 1) * 4] = p0;
      *(short4*)&Qs[swz8(2 * qp + 1, k >> 1) + (k & 1) * 4] = p1;
      const float* f0 = (const float*)&v0;
      const float* f1 = (const float*)&v1;
#pragma unroll
      for (int e = 0; e < 4; e++) {
        int h = 4 * k + e;
        short2 pr;
        pr.x = f2bf(f0[e]);
        pr.y = f2bf(f1[e]);
        *(short2*)&QTs[h * 128 + ((((qp >> 2) ^ (h & 7)) & 15) << 3) + ((2 * qp) & 7)] = pr;
      }
    }
    s0 += __shfl_xor(s0, 1, 64); s0 += __shfl_xor(s0, 2, 64); s0 += __shfl_xor(s0, 4, 64);
    s1 += __shfl_xor(s1, 1, 64); s1 += __shfl_xor(s1, 2, 64); s1 += __shfl_xor(s1, 4, 64);
    if (p == 0) {
      sqm[2 * qp] = qmask[b * Q_ + 2 * qp] ? s0 : -1e12f;
      sqm[2 * qp + 1] = qmask[b * Q_ + 2 * qp + 1] ? s1 : -1e12f;
    }
  }
  __syncthreads();

  int w = tid >> 6, lane = tid & 63;
  int lq = lane & 31, kg = lane >> 5;

  // ---- S^T = Q . X^T : M=q(128), N=c(128), K=h(128) ----
  int wm = w >> 2, wn = w & 3;
  f32x16 acc[2];
#pragma unroll
  for (int mf = 0; mf < 2; mf++)
#pragma unroll
    for (int r = 0; r < 16; r++) acc[mf][r] = 0.f;
  {
    int rA0 = wm * 64 + lq, rA1 = rA0 + 32, rB = wn * 32 + lq;
#pragma unroll
    for (int ks = 0; ks < 8; ks++) {
      int ch = 2 * ks + kg;
      short8 a0 = *(const short8*)&Qs[swz8(rA0, ch)];
      short8 a1 = *(const short8*)&Qs[swz8(rA1, ch)];
      short8 bb = *(const short8*)&Xs[swz8(rB, ch)];
      acc[0] = __builtin_amdgcn_mfma_f32_32x32x16_bf16(a0, bb, acc[0], 0, 0, 0);
      acc[1] = __builtin_amdgcn_mfma_f32_32x32x16_bf16(a1, bb, acc[1], 0, 0, 0);
    }
  }

  // ---- softmax over q per c-column of S^T ----
  int cL = wn * 32 + lq;
  float scc = scv[cL];
  float pmax = -3e38f;
#pragma unroll
  for (int mf = 0; mf < 2; mf++)
#pragma unroll
    for (int g = 0; g < 4; g++) {
      int q0 = wm * 64 + mf * 32 + 8 * g + 4 * kg;
      float4 s4 = *(const float4*)&sqm[q0];
      float sv[4] = {s4.x, s4.y, s4.z, s4.w};
#pragma unroll
      for (int r = 0; r < 4; r++) {
        float Sv = acc[mf][4 * g + r] + scc + sv[r];
        acc[mf][4 * g + r] = Sv;
        pmax = fmaxf(pmax, Sv);
      }
    }
  pmax = fmaxf(pmax, __shfl_xor(pmax, 32, 64));
  if (lane < 32) pm_lds[wm][cL] = pmax;
  __syncthreads();

  float M = fmaxf(pm_lds[0][cL], pm_lds[1][cL]);
  if (wm == 0 && lane < 32) {
    mcv[cL] = cmask[bc0 + cL] ? M : NEGV;
  }
  float psum = 0.f;
#pragma unroll
  for (int mf = 0; mf < 2; mf++)
#pragma unroll
    for (int g = 0; g < 4; g++) {
      int q0 = wm * 64 + mf * 32 + 8 * g + 4 * kg;
      float e0 = __expf(acc[mf][4 * g + 0] - M);
      float e1 = __expf(acc[mf][4 * g + 1] - M);
      float e2 = __expf(acc[mf][4 * g + 2] - M);
      float e3 = __expf(acc[mf][4 * g + 3] - M);
      psum += e0 + e1 + e2 + e3;
      short4 pk;
      pk.x = f2bf(e0); pk.y = f2bf(e1); pk.z = f2bf(e2); pk.w = f2bf(e3);
      *(short4*)&Xs[swz8(cL, q0 >> 3) + (q0 & 7)] = pk;  // a[c][q]
    }
  psum += __shfl_xor(psum, 32, 64);
  if (lane < 32) ps_lds[wm][cL] = psum;
  __syncthreads();

  // ---- c2q = a . qry : M=c(128), N=h(128), K=q(128) ----
  int wm2 = w & 3, wn2 = w >> 2;
  f32x16 o[2];
#pragma unroll
  for (int nf = 0; nf < 2; nf++)
#pragma unroll
    for (int r = 0; r < 16; r++) o[nf][r] = 0.f;
  {
    int rA = wm2 * 32 + lq;
    int rB0 = wn2 * 64 + lq, rB1 = rB0 + 32;
#pragma unroll
    for (int ks = 0; ks < 8; ks++) {
      int ch = 2 * ks + kg;
      short8 af = *(const short8*)&Xs[swz8(rA, ch)];
      short8 b0 = *(const short8*)&QTs[swz8(rB0, ch)];
      short8 b1 = *(const short8*)&QTs[swz8(rB1, ch)];
      o[0] = __builtin_amdgcn_mfma_f32_32x32x16_bf16(af, b0, o[0], 0, 0, 0);
      o[1] = __builtin_amdgcn_mfma_f32_32x32x16_bf16(af, b1, o[1], 0, 0, 0);
    }
  }

  // ---- epilogue: normalize, write G chunks 2,3 ----
  int h0 = wn2 * 64 + lq, h1 = h0 + 32;
#pragma unroll
  for (int g = 0; g < 4; g++) {
    int c0 = wm2 * 32 + 8 * g + 4 * kg;
    float4 z0 = *(const float4*)&ps_lds[0][c0];
    float4 z1 = *(const float4*)&ps_lds[1][c0];
    float zz[4] = {z0.x + z1.x, z0.y + z1.y, z0.z + z1.z, z0.w + z1.w};
#pragma unroll
    for (int r = 0; r < 4; r++) {
      int c = c0 + r;
      float rz = 1.f / zz[r];
      size_t ro = (size_t)(bc0 + c) * (4 * H_);
      const float* crow = ctx + (size_t)(bc0 + c) * H_;
      float ov0 = o[0][4 * g + r] * rz;
      float ov1 = o[1][4 * g + r] * rz;
      float cv0 = crow[h0];
      float cv1 = crow[h1];
      out[ro + H_ + h0] = ov0;
      out[ro + H_ + h1] = ov1;
      out[ro + 2 * H_ + h0] = ov0 * cv0;
      out[ro + 2 * H_ + h1] = ov1 * cv1;
    }
  }
  __syncthreads();  // all c2q reads of Xs done; mcv visible

  // ---- block-local partial q2c ----
  {  // re-stage ctx (bf16) into Xs from registers
    int c = tid >> 2, part = tid & 3;
#pragma unroll
    for (int jj = 0; jj < 8; jj++) {
      int k = part + 4 * jj;
      float4 v = cvr[jj];
      short4 xp;
      xp.x = f2bf(v.x); xp.y = f2bf(v.y); xp.z = f2bf(v.z); xp.w = f2bf(v.w);
      *(short4*)&Xs[swz8(c, k >> 1) + (k & 1) * 4] = xp;
    }
  }
  int l2 = 2 * lane;
  float m0v = mcv[l2], m1v = mcv[l2 + 1];
  float lm = wave_max(fmaxf(m0v, m1v));
  float ew0 = __expf(m0v - lm), ew1 = __expf(m1v - lm);
  float lz = wave_sum(ew0 + ew1);
  if (tid < 64) { wcv[l2] = ew0; wcv[l2 + 1] = ew1; }
  __syncthreads();
  {
    int h = 2 * lane;
    int ch = h >> 3, off = h & 7;
    float ax = 0.f, ay = 0.f;
#pragma unroll
    for (int i = 0; i < 16; i++) {
      int c = w * 16 + i;
      short2 x = *(const short2*)&Xs[swz8(c, ch) + off];
      float wg = wcv[c];
      ax += wg * bf2f(x.x);
      ay += wg * bf2f(x.y);
    }
    pqacc[w][h] = ax;
    pqacc[w][h + 1] = ay;
  }
  __syncthreads();
  float* rec = pw + (size_t)(b * 16 + ct) * REC_;
  if (tid < 128) {
    float s = 0.f;
#pragma unroll
    for (int ww = 0; ww < 8; ww++) s += pqacc[ww][tid];
    rec[8 + tid] = s;
  }
  if (tid == 128) rec[0] = lm;
  if (tid == 129) rec[1] = lz;

  if constexpr (COOP) {
    __threadfence();
    cg::this_grid().sync();

    // combine 16 records of this b (redundant per block)
    const float* base = pw + (size_t)b * 16 * REC_;
    float Mg = -3e38f;
#pragma unroll
    for (int t = 0; t < 16; t++) Mg = fmaxf(Mg, base[t * REC_]);
    float Zg = 0.f;
    float et[16];
#pragma unroll
    for (int t = 0; t < 16; t++) {
      et[t] = __expf(base[t * REC_] - Mg);
      Zg += et[t] * base[t * REC_ + 1];
    }
    float rzg = 1.f / Zg;
    if (tid < 128) {
      float s = 0.f;
#pragma unroll
      for (int t = 0; t < 16; t++) s += et[t] * base[t * REC_ + 8 + tid];
      q2cs[tid] = s * rzg;
    }
    __syncthreads();

    // G chunk 4 = ctx * q2c from register-held ctx
    int c = tid >> 2, part = tid & 3;
    float* orow = out + (size_t)(bc0 + c) * (4 * H_) + 3 * H_;
#pragma unroll
    for (int jj = 0; jj < 8; jj++) {
      int k = part + 4 * jj;
      float4 g = *(const float4*)&q2cs[4 * k];
      float4 v = cvr[jj];
      float4 r = make_float4(v.x * g.x, v.y * g.y, v.z * g.z, v.w * g.w);
      *(float4*)&orow[4 * k] = r;
    }
  }
}

// Fallback combine: q2c[b][128] from records
__global__ void k_comb(const float* __restrict__ pw, float* __restrict__ q2c) {
  int b = blockIdx.x;
  int tid = threadIdx.x;  // 128
  const float* base = pw + (size_t)b * 16 * REC_;
  float Mg = -3e38f;
#pragma unroll
  for (int t = 0; t < 16; t++) Mg = fmaxf(Mg, base[t * REC_]);
  float Zg = 0.f;
  float et[16];
#pragma unroll
  for (int t = 0; t < 16; t++) {
    et[t] = __expf(base[t * REC_] - Mg);
    Zg += et[t] * base[t * REC_ + 1];
  }
  float s = 0.f;
#pragma unroll
  for (int t = 0; t < 16; t++) s += et[t] * base[t * REC_ + 8 + tid];
  q2c[b * H_ + tid] = s / Zg;
}

// Fallback chunk 4
__global__ void k4_out(const float* __restrict__ ctx,
                       const float* __restrict__ q2c, float* __restrict__ out) {
  int t = blockIdx.x * 256 + threadIdx.x;
  int h4 = t & 31;
  int bc = t >> 5;
  int b = bc >> 11;
  float4 cvv = *(const float4*)&ctx[(size_t)t * 4];
  float4 g = *(const float4*)&q2c[b * H_ + h4 * 4];
  float4 r = make_float4(cvv.x * g.x, cvv.y * g.y, cvv.z * g.z, cvv.w * g.w);
  *(float4*)&out[((size_t)bc) * (4 * H_) + 3 * H_ + h4 * 4] = r;
}

extern "C" void kernel_launch(void* const* d_in, const int* in_sizes, int n_in,
                              void* d_out, int out_size, void* d_ws,
                              size_t ws_size, hipStream_t stream) {
  const float* ctx = (const float*)d_in[0];
  const float* qry = (const float*)d_in[1];
  const float* W = (const float*)d_in[2];
  const int* cmask = (const int*)d_in[3];
  const int* qmask = (const int*)d_in[4];
  float* out = (float*)d_out;
  float* ws = (float*)d_ws;

  float* pw = ws;                       // 256 records * 136 floats
  float* q2cg = ws + 256 * REC_;        // fallback q2c [B][H]

  void* args[] = {(void*)&ctx, (void*)&qry, (void*)&W, (void*)&cmask,
                  (void*)&qmask, (void*)&out, (void*)&pw};
  hipError_t e = hipLaunchCooperativeKernel((const void*)(k_mono<1>),
                                            dim3(B_ * 16), dim3(512), args, 0,
                                            stream);
  if (e != hipSuccess) {
    // fallback: same kernel w/o grid sync, then tiny combine + chunk4 pass
    k_mono<0><<<B_ * 16, 512, 0, stream>>>(ctx, qry, W, cmask, qmask, out, pw);
    k_comb<<<B_, 128, 0, stream>>>(pw, q2cg);
    k4_out<<<4096, 256, 0, stream>>>(ctx, q2cg, out);
  }
}

// Round 5
// 35.867 us; speedup vs baseline: 3.1337x; 3.1337x over previous
//
#include <hip/hip_runtime.h>
#include <math.h>

#define B_ 16
#define C_ 2048
#define Q_ 128
#define H_ 128
#define NEGV (-1000000000.0f)
#define REC_ 136  // record: [0]=m, [1]=z, [8..135]=partial q2c (unnormalized)

typedef short short8 __attribute__((ext_vector_type(8)));
typedef float f32x16 __attribute__((ext_vector_type(16)));
typedef float f32x4 __attribute__((ext_vector_type(4)));

__device__ __forceinline__ short f2bf(float f) {
  unsigned u = __builtin_bit_cast(unsigned, f);
  u += 0x7fffu + ((u >> 16) & 1u);
  return (short)(u >> 16);
}

// swizzled short-index of 16B chunk `ch` in row `row` of a [rows][128] bf16 tile
__device__ __forceinline__ int swz(int row, int ch) {
  return row * 128 + (((ch ^ (row & 7)) & 15) << 3);
}

__device__ __forceinline__ void nt_store4(float* p, float4 v) {
  __builtin_nontemporal_store(__builtin_bit_cast(f32x4, v), (f32x4*)p);
}

// K1: per (b, 64-c tile): S^T via MFMA, softmax over q, c2q via MFMA,
// G chunks 1-3, maxq. 512 thr = 8 waves, 2 blocks/CU (LDS ~51KB).
__global__ __launch_bounds__(512, 4) void k1_main(
    const float* __restrict__ ctx, const float* __restrict__ qry,
    const float* __restrict__ W, const int* __restrict__ cmask,
    const int* __restrict__ qmask, float* __restrict__ out,
    float* __restrict__ maxq) {
  __shared__ short QXs[16384];      // qry[q][h] bf16 swz; later qry^T[h][q] bf16 swz
  __shared__ short Xs[64 * 128];    // x[c][h] bf16 swz; later a[c][q]
  __shared__ float scv[64];         // sc[c]
  __shared__ float sqm[128];        // qmask ? sq[q] : -1e12
  __shared__ float pm_lds[4][64];   // per-q-quarter max partials
  __shared__ float ps_lds[4][64];   // per-q-quarter sum partials

  int b = blockIdx.x >> 5;
  int ct = blockIdx.x & 31;
  int tid = threadIdx.x;
  int bc0 = b * C_ + ct * 64;

  // ---- stage ctx tile (64 rows): out chunk1 (NT), sc[c], Xs ----
  {
    int c = tid >> 3, part = tid & 7;
    const float* crow = ctx + (size_t)(bc0 + c) * H_;
    float* orow = out + (size_t)(bc0 + c) * (4 * H_);
    float wsum = 0.f;
#pragma unroll
    for (int jj = 0; jj < 4; jj++) {
      int k = part + 8 * jj;  // float4 chunk 0..31
      float4 v = *(const float4*)&crow[4 * k];
      nt_store4(&orow[4 * k], v);  // G chunk 1 = ctx (exact fp32)
      float4 wc = *(const float4*)&W[4 * k];
      float4 wq = *(const float4*)&W[2 * H_ + 4 * k];
      wsum += v.x * wc.x + v.y * wc.y + v.z * wc.z + v.w * wc.w;
      short4 xp;
      xp.x = f2bf(v.x * wq.x);
      xp.y = f2bf(v.y * wq.y);
      xp.z = f2bf(v.z * wq.z);
      xp.w = f2bf(v.w * wq.w);
      *(short4*)&Xs[swz(c, k >> 1) + (k & 1) * 4] = xp;
    }
    wsum += __shfl_xor(wsum, 1, 64);
    wsum += __shfl_xor(wsum, 2, 64);
    wsum += __shfl_xor(wsum, 4, 64);
    if (part == 0) scv[c] = wsum;
  }
  // ---- stage qry rows (bf16) + sq in-block ----
  {
    int q = tid >> 2, p = tid & 3;
    const float* qrow = qry + (size_t)(b * Q_ + q) * H_;
    float s = 0.f;
#pragma unroll
    for (int jj = 0; jj < 8; jj++) {
      int k = p + 4 * jj;
      float4 v = *(const float4*)&qrow[4 * k];
      float4 wq4 = *(const float4*)&W[H_ + 4 * k];
      s += v.x * wq4.x + v.y * wq4.y + v.z * wq4.z + v.w * wq4.w;
      short4 pk;
      pk.x = f2bf(v.x); pk.y = f2bf(v.y); pk.z = f2bf(v.z); pk.w = f2bf(v.w);
      *(short4*)&QXs[swz(q, k >> 1) + (k & 1) * 4] = pk;
    }
    s += __shfl_xor(s, 1, 64);
    s += __shfl_xor(s, 2, 64);
    if (p == 0) sqm[q] = qmask[b * Q_ + q] ? s : -1e12f;
  }
  __syncthreads();

  int w = tid >> 6, lane = tid & 63;
  int lq = lane & 31, kg = lane >> 5;

  // ---- GEMM1: S^T = Q . X^T : M=q(128, 4 frags), N=c(64, 2 frags) ----
  int wm = w >> 1, wn = w & 1;  // wave -> (q frag, c frag)
  f32x16 acc;
#pragma unroll
  for (int r = 0; r < 16; r++) acc[r] = 0.f;
  {
    int rA = wm * 32 + lq, rB = wn * 32 + lq;
#pragma unroll
    for (int ks = 0; ks < 8; ks++) {
      int ch = 2 * ks + kg;
      short8 a = *(const short8*)&QXs[swz(rA, ch)];
      short8 bb = *(const short8*)&Xs[swz(rB, ch)];
      acc = __builtin_amdgcn_mfma_f32_32x32x16_bf16(a, bb, acc, 0, 0, 0);
    }
  }

  // ---- softmax over q per c-column ----
  int cL = wn * 32 + lq;
  float scc = scv[cL];
  float pmax = -3e38f;
#pragma unroll
  for (int g = 0; g < 4; g++) {
    int q0 = wm * 32 + 8 * g + 4 * kg;
    float4 s4 = *(const float4*)&sqm[q0];
    float sv[4] = {s4.x, s4.y, s4.z, s4.w};
#pragma unroll
    for (int r = 0; r < 4; r++) {
      float Sv = acc[4 * g + r] + scc + sv[r];
      acc[4 * g + r] = Sv;
      pmax = fmaxf(pmax, Sv);
    }
  }
  pmax = fmaxf(pmax, __shfl_xor(pmax, 32, 64));
  if (lane < 32) pm_lds[wm][cL] = pmax;
  __syncthreads();  // also: all GEMM1 reads of QXs/Xs complete

  float M = fmaxf(fmaxf(pm_lds[0][cL], pm_lds[1][cL]),
                  fmaxf(pm_lds[2][cL], pm_lds[3][cL]));
  if (wm == 0 && lane < 32) {
    maxq[bc0 + cL] = cmask[bc0 + cL] ? M : NEGV;
  }
  float psum = 0.f;
#pragma unroll
  for (int g = 0; g < 4; g++) {
    int q0 = wm * 32 + 8 * g + 4 * kg;
    float e0 = __expf(acc[4 * g + 0] - M);
    float e1 = __expf(acc[4 * g + 1] - M);
    float e2 = __expf(acc[4 * g + 2] - M);
    float e3 = __expf(acc[4 * g + 3] - M);
    psum += e0 + e1 + e2 + e3;
    short4 pk;
    pk.x = f2bf(e0); pk.y = f2bf(e1); pk.z = f2bf(e2); pk.w = f2bf(e3);
    *(short4*)&Xs[swz(cL, q0 >> 3) + (q0 & 7)] = pk;  // a[c][q]
  }
  psum += __shfl_xor(psum, 32, 64);
  if (lane < 32) ps_lds[wm][cL] = psum;

  // ---- rebuild QXs as qry^T[h][q] (Q rows dead after GEMM1) ----
  {
    int qp = tid >> 3, p = tid & 7;
    const float* q0r = qry + (size_t)(b * Q_ + 2 * qp) * H_;
    const float* q1r = q0r + H_;
#pragma unroll
    for (int jj = 0; jj < 4; jj++) {
      int k = p + 8 * jj;
      float4 v0 = *(const float4*)&q0r[4 * k];
      float4 v1 = *(const float4*)&q1r[4 * k];
      const float* f0 = (const float*)&v0;
      const float* f1 = (const float*)&v1;
#pragma unroll
      for (int e = 0; e < 4; e++) {
        int h = 4 * k + e;
        short2 pr;
        pr.x = f2bf(f0[e]);
        pr.y = f2bf(f1[e]);
        *(short2*)&QXs[swz(h, qp >> 2) + ((2 * qp) & 7)] = pr;
      }
    }
  }
  __syncthreads();

  // ---- GEMM2: c2q = a . qry : M=c(64, 2 frags), N=h(128, 4 frags) ----
  int wm2 = w & 1, wn2 = w >> 1;  // wave -> (c frag, h frag)
  f32x16 o;
#pragma unroll
  for (int r = 0; r < 16; r++) o[r] = 0.f;
  {
    int rA = wm2 * 32 + lq, rB = wn2 * 32 + lq;
#pragma unroll
    for (int ks = 0; ks < 8; ks++) {
      int ch = 2 * ks + kg;
      short8 af = *(const short8*)&Xs[swz(rA, ch)];
      short8 bf_ = *(const short8*)&QXs[swz(rB, ch)];
      o = __builtin_amdgcn_mfma_f32_32x32x16_bf16(af, bf_, o, 0, 0, 0);
    }
  }

  // ---- epilogue: normalize by Z, write G chunks 2,3 ----
  int h = wn2 * 32 + lq;
#pragma unroll
  for (int g = 0; g < 4; g++) {
    int c0 = wm2 * 32 + 8 * g + 4 * kg;
    float4 z0 = *(const float4*)&ps_lds[0][c0];
    float4 z1 = *(const float4*)&ps_lds[1][c0];
    float4 z2 = *(const float4*)&ps_lds[2][c0];
    float4 z3 = *(const float4*)&ps_lds[3][c0];
    float zz[4] = {z0.x + z1.x + z2.x + z3.x, z0.y + z1.y + z2.y + z3.y,
                   z0.z + z1.z + z2.z + z3.z, z0.w + z1.w + z2.w + z3.w};
#pragma unroll
    for (int r = 0; r < 4; r++) {
      int c = c0 + r;
      float rz = 1.f / zz[r];
      size_t ro = (size_t)(bc0 + c) * (4 * H_);
      float ov = o[4 * g + r] * rz;
      float cv = ctx[(size_t)(bc0 + c) * H_ + h];
      out[ro + H_ + h] = ov;
      out[ro + 2 * H_ + h] = ov * cv;
    }
  }
}

// K3: per (b, 128-c chunk): local m/z over masked maxq + unnormalized partial
// q2c vector; writes a 136-float record. No atomics.
__global__ __launch_bounds__(256) void k3_part(const float* __restrict__ ctx,
                                               const float* __restrict__ maxq,
                                               float* __restrict__ pw) {
  __shared__ float red[128];
  __shared__ float wcv[128];
  __shared__ float4 red4[256];
  int b = blockIdx.x >> 4, chunk = blockIdx.x & 15;
  int tid = threadIdx.x;
  int cbase = b * C_ + chunk * 128;

  float v = (tid < 128) ? maxq[cbase + tid] : -3e38f;
  if (tid < 128) red[tid] = v;
  __syncthreads();
  for (int s = 64; s; s >>= 1) {
    if (tid < s) red[tid] = fmaxf(red[tid], red[tid + s]);
    __syncthreads();
  }
  float M = red[0];
  __syncthreads();
  float e = (tid < 128) ? __expf(v - M) : 0.f;
  if (tid < 128) {
    wcv[tid] = e;
    red[tid] = e;
  }
  __syncthreads();
  for (int s = 64; s; s >>= 1) {
    if (tid < s) red[tid] += red[tid + s];
    __syncthreads();
  }
  float z = red[0];

  int h4 = tid & 31, cl = tid >> 5;
  float4 acc = {0.f, 0.f, 0.f, 0.f};
#pragma unroll
  for (int i = 0; i < 16; i++) {
    int c = cl * 16 + i;
    float wg = wcv[c];
    float4 cv = *(const float4*)&ctx[(size_t)(cbase + c) * H_ + 4 * h4];
    acc.x += wg * cv.x;
    acc.y += wg * cv.y;
    acc.z += wg * cv.z;
    acc.w += wg * cv.w;
  }
  red4[tid] = acc;
  __syncthreads();
  for (int s = 4; s; s >>= 1) {
    if (cl < s) {
      float4 o2 = red4[(cl + s) * 32 + h4];
      acc.x += o2.x; acc.y += o2.y; acc.z += o2.z; acc.w += o2.w;
      red4[tid] = acc;
    }
    __syncthreads();
  }
  float* rec = pw + (size_t)blockIdx.x * REC_;
  if (cl == 0) *(float4*)&rec[8 + 4 * h4] = acc;
  if (tid == 0) { rec[0] = M; rec[1] = z; }
}

// K_comb: q2c[b][128] from 16 records (log-sum-exp combine)
__global__ void k_comb(const float* __restrict__ pw, float* __restrict__ q2c) {
  int b = blockIdx.x;
  int tid = threadIdx.x;  // 128
  const float* base = pw + (size_t)b * 16 * REC_;
  float Mg = -3e38f;
#pragma unroll
  for (int t = 0; t < 16; t++) Mg = fmaxf(Mg, base[t * REC_]);
  float Zg = 0.f;
  float et[16];
#pragma unroll
  for (int t = 0; t < 16; t++) {
    et[t] = __expf(base[t * REC_] - Mg);
    Zg += et[t] * base[t * REC_ + 1];
  }
  float s = 0.f;
#pragma unroll
  for (int t = 0; t < 16; t++) s += et[t] * base[t * REC_ + 8 + tid];
  q2c[b * H_ + tid] = s / Zg;
}

// K4: G chunk 4 = ctx * q2c (broadcast over c), NT stores
__global__ void k4_out(const float* __restrict__ ctx,
                       const float* __restrict__ q2c, float* __restrict__ out) {
  int t = blockIdx.x * 256 + threadIdx.x;
  int h4 = t & 31;
  int bc = t >> 5;
  int b = bc >> 11;
  float4 cvv = *(const float4*)&ctx[(size_t)t * 4];
  float4 g = *(const float4*)&q2c[b * H_ + h4 * 4];
  float4 r = make_float4(cvv.x * g.x, cvv.y * g.y, cvv.z * g.z, cvv.w * g.w);
  nt_store4(&out[((size_t)bc) * (4 * H_) + 3 * H_ + h4 * 4], r);
}

extern "C" void kernel_launch(void* const* d_in, const int* in_sizes, int n_in,
                              void* d_out, int out_size, void* d_ws,
                              size_t ws_size, hipStream_t stream) {
  const float* ctx = (const float*)d_in[0];
  const float* qry = (const float*)d_in[1];
  const float* W = (const float*)d_in[2];
  const int* cmask = (const int*)d_in[3];
  const int* qmask = (const int*)d_in[4];
  float* out = (float*)d_out;
  float* ws = (float*)d_ws;

  float* maxq = ws;                  // B*C
  float* pw = ws + B_ * C_;          // 256 records * REC_
  float* q2c = pw + 256 * REC_;      // B*H

  k1_main<<<B_ * 32, 512, 0, stream>>>(ctx, qry, W, cmask, qmask, out, maxq);
  k3_part<<<B_ * 16, 256, 0, stream>>>(ctx, maxq, pw);
  k_comb<<<B_, 128, 0, stream>>>(pw, q2c);
  k4_out<<<4096, 256, 0, stream>>>(ctx, q2c, out);
}

// Round 6
// 28.514 us; speedup vs baseline: 3.9417x; 1.2578x over previous
//
#include <hip/hip_runtime.h>
#include <math.h>

#define B_ 16
#define C_ 2048
#define Q_ 128
#define H_ 128
#define NEGV (-1000000000.0f)
#define REC_ 136  // record: [0]=m, [1]=z, [8..135]=partial q2c (unnormalized)

typedef short short8 __attribute__((ext_vector_type(8)));
typedef float f32x16 __attribute__((ext_vector_type(16)));
typedef float f32x4 __attribute__((ext_vector_type(4)));

__device__ __forceinline__ short f2bf(float f) {
  unsigned u = __builtin_bit_cast(unsigned, f);
  u += 0x7fffu + ((u >> 16) & 1u);
  return (short)(u >> 16);
}

// swizzled short-index of 16B chunk `ch` in row `row` of a [rows][128] bf16 tile
__device__ __forceinline__ int swz(int row, int ch) {
  return row * 128 + (((ch ^ (row & 7)) & 15) << 3);
}

__device__ __forceinline__ void nt_store4(float* p, float4 v) {
  __builtin_nontemporal_store(__builtin_bit_cast(f32x4, v), (f32x4*)p);
}

__device__ __forceinline__ float wave_max(float v) {
#pragma unroll
  for (int off = 32; off; off >>= 1) v = fmaxf(v, __shfl_xor(v, off, 64));
  return v;
}
__device__ __forceinline__ float wave_sum(float v) {
#pragma unroll
  for (int off = 32; off; off >>= 1) v += __shfl_xor(v, off, 64);
  return v;
}

// K1: per (b, 64-c tile): S^T via MFMA, softmax over q, c2q via MFMA,
// G chunks 1-3, and the block's q2c partial record. 512 thr = 8 waves,
// 2 blocks/CU (LDS ~52KB, VGPR<=128).
__global__ __launch_bounds__(512, 4) void k1_main(
    const float* __restrict__ ctx, const float* __restrict__ qry,
    const float* __restrict__ W, const int* __restrict__ cmask,
    const int* __restrict__ qmask, float* __restrict__ out,
    float* __restrict__ pw) {
  __shared__ short QXs[16384];      // qry[q][h] bf16 swz; later qry^T[h][q] bf16 swz
  __shared__ short Xs[64 * 128];    // x[c][h] bf16 swz; later a[c][q]
  __shared__ float scv[64];         // sc[c]
  __shared__ float sqm[128];        // qmask ? sq[q] : -1e12
  __shared__ float pm_lds[4][64];   // per-q-quarter max partials
  __shared__ float ps_lds[4][64];   // per-q-quarter sum partials
  __shared__ float mcv[64];         // masked per-c max (q2c path)
  __shared__ float wcv[64];         // exp(mcv - local m)
  __shared__ float mzl[2];          // local m, z
  __shared__ float pqacc[4][128];   // q2c partial groups

  int b = blockIdx.x >> 5;
  int ct = blockIdx.x & 31;
  int tid = threadIdx.x;
  int bc0 = b * C_ + ct * 64;

  // ---- stage ctx tile (64 rows): out chunk1 (NT), sc[c], Xs ----
  {
    int c = tid >> 3, part = tid & 7;
    const float* crow = ctx + (size_t)(bc0 + c) * H_;
    float* orow = out + (size_t)(bc0 + c) * (4 * H_);
    float wsum = 0.f;
#pragma unroll
    for (int jj = 0; jj < 4; jj++) {
      int k = part + 8 * jj;  // float4 chunk 0..31
      float4 v = *(const float4*)&crow[4 * k];
      nt_store4(&orow[4 * k], v);  // G chunk 1 = ctx (exact fp32)
      float4 wc = *(const float4*)&W[4 * k];
      float4 wq = *(const float4*)&W[2 * H_ + 4 * k];
      wsum += v.x * wc.x + v.y * wc.y + v.z * wc.z + v.w * wc.w;
      short4 xp;
      xp.x = f2bf(v.x * wq.x);
      xp.y = f2bf(v.y * wq.y);
      xp.z = f2bf(v.z * wq.z);
      xp.w = f2bf(v.w * wq.w);
      *(short4*)&Xs[swz(c, k >> 1) + (k & 1) * 4] = xp;
    }
    wsum += __shfl_xor(wsum, 1, 64);
    wsum += __shfl_xor(wsum, 2, 64);
    wsum += __shfl_xor(wsum, 4, 64);
    if (part == 0) scv[c] = wsum;
  }
  // ---- stage qry rows (bf16) + sq in-block ----
  {
    int q = tid >> 2, p = tid & 3;
    const float* qrow = qry + (size_t)(b * Q_ + q) * H_;
    float s = 0.f;
#pragma unroll
    for (int jj = 0; jj < 8; jj++) {
      int k = p + 4 * jj;
      float4 v = *(const float4*)&qrow[4 * k];
      float4 wq4 = *(const float4*)&W[H_ + 4 * k];
      s += v.x * wq4.x + v.y * wq4.y + v.z * wq4.z + v.w * wq4.w;
      short4 pk;
      pk.x = f2bf(v.x); pk.y = f2bf(v.y); pk.z = f2bf(v.z); pk.w = f2bf(v.w);
      *(short4*)&QXs[swz(q, k >> 1) + (k & 1) * 4] = pk;
    }
    s += __shfl_xor(s, 1, 64);
    s += __shfl_xor(s, 2, 64);
    if (p == 0) sqm[q] = qmask[b * Q_ + q] ? s : -1e12f;
  }
  __syncthreads();

  int w = tid >> 6, lane = tid & 63;
  int lq = lane & 31, kg = lane >> 5;

  // ---- GEMM1: S^T = Q . X^T : M=q(128, 4 frags), N=c(64, 2 frags) ----
  int wm = w >> 1, wn = w & 1;  // wave -> (q frag, c frag)
  f32x16 acc;
#pragma unroll
  for (int r = 0; r < 16; r++) acc[r] = 0.f;
  {
    int rA = wm * 32 + lq, rB = wn * 32 + lq;
#pragma unroll
    for (int ks = 0; ks < 8; ks++) {
      int ch = 2 * ks + kg;
      short8 a = *(const short8*)&QXs[swz(rA, ch)];
      short8 bb = *(const short8*)&Xs[swz(rB, ch)];
      acc = __builtin_amdgcn_mfma_f32_32x32x16_bf16(a, bb, acc, 0, 0, 0);
    }
  }

  // ---- softmax over q per c-column ----
  int cL = wn * 32 + lq;
  float scc = scv[cL];
  float pmax = -3e38f;
#pragma unroll
  for (int g = 0; g < 4; g++) {
    int q0 = wm * 32 + 8 * g + 4 * kg;
    float4 s4 = *(const float4*)&sqm[q0];
    float sv[4] = {s4.x, s4.y, s4.z, s4.w};
#pragma unroll
    for (int r = 0; r < 4; r++) {
      float Sv = acc[4 * g + r] + scc + sv[r];
      acc[4 * g + r] = Sv;
      pmax = fmaxf(pmax, Sv);
    }
  }
  pmax = fmaxf(pmax, __shfl_xor(pmax, 32, 64));
  if (lane < 32) pm_lds[wm][cL] = pmax;
  __syncthreads();  // also: all GEMM1 reads of QXs/Xs complete

  float M = fmaxf(fmaxf(pm_lds[0][cL], pm_lds[1][cL]),
                  fmaxf(pm_lds[2][cL], pm_lds[3][cL]));
  if (wm == 0 && lane < 32) {
    mcv[cL] = cmask[bc0 + cL] ? M : NEGV;
  }
  float psum = 0.f;
#pragma unroll
  for (int g = 0; g < 4; g++) {
    int q0 = wm * 32 + 8 * g + 4 * kg;
    float e0 = __expf(acc[4 * g + 0] - M);
    float e1 = __expf(acc[4 * g + 1] - M);
    float e2 = __expf(acc[4 * g + 2] - M);
    float e3 = __expf(acc[4 * g + 3] - M);
    psum += e0 + e1 + e2 + e3;
    short4 pk;
    pk.x = f2bf(e0); pk.y = f2bf(e1); pk.z = f2bf(e2); pk.w = f2bf(e3);
    *(short4*)&Xs[swz(cL, q0 >> 3) + (q0 & 7)] = pk;  // a[c][q]
  }
  psum += __shfl_xor(psum, 32, 64);
  if (lane < 32) ps_lds[wm][cL] = psum;

  // ---- rebuild QXs as qry^T[h][q] (Q rows dead after GEMM1) ----
  {
    int qp = tid >> 3, p = tid & 7;
    const float* q0r = qry + (size_t)(b * Q_ + 2 * qp) * H_;
    const float* q1r = q0r + H_;
#pragma unroll
    for (int jj = 0; jj < 4; jj++) {
      int k = p + 8 * jj;
      float4 v0 = *(const float4*)&q0r[4 * k];
      float4 v1 = *(const float4*)&q1r[4 * k];
      const float* f0 = (const float*)&v0;
      const float* f1 = (const float*)&v1;
#pragma unroll
      for (int e = 0; e < 4; e++) {
        int h = 4 * k + e;
        short2 pr;
        pr.x = f2bf(f0[e]);
        pr.y = f2bf(f1[e]);
        *(short2*)&QXs[swz(h, qp >> 2) + ((2 * qp) & 7)] = pr;
      }
    }
  }
  __syncthreads();

  // ---- GEMM2: c2q = a . qry : M=c(64, 2 frags), N=h(128, 4 frags) ----
  int wm2 = w & 1, wn2 = w >> 1;  // wave -> (c frag, h frag)
  f32x16 o;
#pragma unroll
  for (int r = 0; r < 16; r++) o[r] = 0.f;
  {
    int rA = wm2 * 32 + lq, rB = wn2 * 32 + lq;
#pragma unroll
    for (int ks = 0; ks < 8; ks++) {
      int ch = 2 * ks + kg;
      short8 af = *(const short8*)&Xs[swz(rA, ch)];
      short8 bf_ = *(const short8*)&QXs[swz(rB, ch)];
      o = __builtin_amdgcn_mfma_f32_32x32x16_bf16(af, bf_, o, 0, 0, 0);
    }
  }

  // ---- epilogue: normalize by Z, write G chunks 2,3 ----
  int h = wn2 * 32 + lq;
#pragma unroll
  for (int g = 0; g < 4; g++) {
    int c0 = wm2 * 32 + 8 * g + 4 * kg;
    float4 z0 = *(const float4*)&ps_lds[0][c0];
    float4 z1 = *(const float4*)&ps_lds[1][c0];
    float4 z2 = *(const float4*)&ps_lds[2][c0];
    float4 z3 = *(const float4*)&ps_lds[3][c0];
    float zz[4] = {z0.x + z1.x + z2.x + z3.x, z0.y + z1.y + z2.y + z3.y,
                   z0.z + z1.z + z2.z + z3.z, z0.w + z1.w + z2.w + z3.w};
#pragma unroll
    for (int r = 0; r < 4; r++) {
      int c = c0 + r;
      float rz = 1.f / zz[r];
      size_t ro = (size_t)(bc0 + c) * (4 * H_);
      float ov = o[4 * g + r] * rz;
      float cv = ctx[(size_t)(bc0 + c) * H_ + h];
      out[ro + H_ + h] = ov;
      out[ro + 2 * H_ + h] = ov * cv;
    }
  }

  // ---- q2c partial record: local m/z over mcv + weighted ctx column-sum ----
  // mcv was written before the pre-GEMM2 __syncthreads -> visible here.
  if (tid < 64) {
    float mv = mcv[tid];
    float lm = wave_max(mv);
    float ew = __expf(mv - lm);
    wcv[tid] = ew;
    float lz = wave_sum(ew);
    if (tid == 0) { mzl[0] = lm; mzl[1] = lz; }
  }
  __syncthreads();
  {
    int hh = tid & 127, grp = tid >> 7;  // 4 groups x 16 c-rows
    const float* cb = ctx + (size_t)bc0 * H_;
    float a = 0.f;
#pragma unroll
    for (int i = 0; i < 16; i++) {
      int c = grp * 16 + i;
      a += wcv[c] * cb[(size_t)c * H_ + hh];
    }
    pqacc[grp][hh] = a;
  }
  __syncthreads();
  float* rec = pw + (size_t)blockIdx.x * REC_;
  if (tid < 128) {
    rec[8 + tid] = pqacc[0][tid] + pqacc[1][tid] + pqacc[2][tid] + pqacc[3][tid];
  }
  if (tid == 128) rec[0] = mzl[0];
  if (tid == 129) rec[1] = mzl[1];
}

// K4: per (b, 64-c tile): combine the 32 records of batch b (redundant,
// L2-hot) -> q2c in LDS, then write G chunk 4 = ctx * q2c. 256 threads.
__global__ __launch_bounds__(256) void k4_out(const float* __restrict__ ctx,
                                              const float* __restrict__ pw,
                                              float* __restrict__ out) {
  __shared__ float q2cs[128];
  int b = blockIdx.x >> 5;
  int ct = blockIdx.x & 31;
  int tid = threadIdx.x;
  int bc0 = b * C_ + ct * 64;

  if (tid < 128) {
    const float* base = pw + (size_t)b * 32 * REC_;
    float Mg = -3e38f;
#pragma unroll
    for (int t = 0; t < 32; t++) Mg = fmaxf(Mg, base[t * REC_]);
    float Zg = 0.f, s = 0.f;
#pragma unroll
    for (int t = 0; t < 32; t++) {
      float et = __expf(base[t * REC_] - Mg);
      Zg += et * base[t * REC_ + 1];
      s += et * base[t * REC_ + 8 + tid];
    }
    q2cs[tid] = s / Zg;
  }
  __syncthreads();

  int c = tid >> 2, part = tid & 3;  // 64 rows, 4 parts x 8 float4
  const float* crow = ctx + (size_t)(bc0 + c) * H_;
  float* orow = out + (size_t)(bc0 + c) * (4 * H_) + 3 * H_;
#pragma unroll
  for (int jj = 0; jj < 8; jj++) {
    int k = part + 4 * jj;
    float4 v = *(const float4*)&crow[4 * k];
    float4 g = *(const float4*)&q2cs[4 * k];
    nt_store4(&orow[4 * k],
              make_float4(v.x * g.x, v.y * g.y, v.z * g.z, v.w * g.w));
  }
}

extern "C" void kernel_launch(void* const* d_in, const int* in_sizes, int n_in,
                              void* d_out, int out_size, void* d_ws,
                              size_t ws_size, hipStream_t stream) {
  const float* ctx = (const float*)d_in[0];
  const float* qry = (const float*)d_in[1];
  const float* W = (const float*)d_in[2];
  const int* cmask = (const int*)d_in[3];
  const int* qmask = (const int*)d_in[4];
  float* out = (float*)d_out;
  float* pw = (float*)d_ws;  // 512 records * REC_ floats

  k1_main<<<B_ * 32, 512, 0, stream>>>(ctx, qry, W, cmask, qmask, out, pw);
  k4_out<<<B_ * 32, 256, 0, stream>>>(ctx, pw, out);
}